// Round 3
// baseline (696.499 us; speedup 1.0000x reference)
//
#include <hip/hip_runtime.h>
#include <hip/hip_bf16.h>
#include <math.h>

#define BATCH 2048
#define NFEAT 7
#define CARD 10000
#define CONCAT 256
#define P_HID 512
#define K_TOT 65536

#define BM 128
#define BN 128
#define BK 64
#define KSPLIT 8

using short8  = __attribute__((ext_vector_type(8))) short;
using floatx4 = __attribute__((ext_vector_type(4))) float;

__device__ __forceinline__ float bf2f(ushort u) {
    unsigned int x = ((unsigned int)u) << 16;
    return __builtin_bit_cast(float, x);
}
__device__ __forceinline__ ushort f2bf(float f) {
    unsigned int x = __builtin_bit_cast(unsigned int, f);
    x += 0x7fffu + ((x >> 16) & 1u);   // round-to-nearest-even
    return (ushort)(x >> 16);
}

// ---------------------------------------------------------------------------
// Kernel 1: dense MLP + embedding gather + per-feature sparse MLPs -> concat
// (bf16, row-major 2048x256). One block (1 wave, 64 threads) per batch row.
// tokenizers == arange(CARD), so argmax(sparse==tokenizers) == sparse value.
// Inputs are fp32 (harness: float32 -> float*, int64 -> int32*).
// ---------------------------------------------------------------------------
__global__ void build_concat(
    const float* __restrict__ dense, const int* __restrict__ sparse,
    const float* __restrict__ emb,
    const float* __restrict__ dw1, const float* __restrict__ db1,
    const float* __restrict__ dw2, const float* __restrict__ db2,
    const float* __restrict__ sw1, const float* __restrict__ sb1,
    const float* __restrict__ sw2, const float* __restrict__ sb2,
    ushort* __restrict__ cbf)
{
    __shared__ float xs[13];
    __shared__ float bufA[64];
    __shared__ float bufB[64];
    const int b = blockIdx.x, t = threadIdx.x;

    if (t < 13) xs[t] = dense[b * 13 + t];
    __syncthreads();

    float h = db1[t];
#pragma unroll
    for (int d = 0; d < 13; ++d) h += xs[d] * dw1[d * 64 + t];
    bufA[t] = fmaxf(h, 0.f);
    __syncthreads();

    if (t < 32) {
        float o = db2[t];
#pragma unroll
        for (int k = 0; k < 64; ++k) o += bufA[k] * dw2[k * 32 + t];
        cbf[b * 256 + t] = f2bf(o);
    }

    for (int f = 0; f < NFEAT; ++f) {
        __syncthreads();                     // protect bufA/bufB reuse
        const int idx = sparse[b * NFEAT + f];
        bufB[t] = emb[((size_t)(f * CARD + idx)) * 64 + t];
        __syncthreads();
        float s = sb1[f * 64 + t];
#pragma unroll
        for (int e = 0; e < 64; ++e) s += bufB[e] * sw1[(f * 64 + e) * 64 + t];
        bufA[t] = fmaxf(s, 0.f);
        __syncthreads();
        if (t < 32) {
            float o = sb2[f * 32 + t];
#pragma unroll
            for (int k = 0; k < 64; ++k) o += bufA[k] * sw2[(f * 64 + k) * 32 + t];
            cbf[b * 256 + 32 + f * 32 + t] = f2bf(o);
        }
    }
}

// ---------------------------------------------------------------------------
// Kernel 2: pw1 (65536x512 f32) -> pw1T (512x65536 bf16), tiled transpose.
// ---------------------------------------------------------------------------
__global__ void transpose_pw1(const float* __restrict__ pw1,
                              ushort* __restrict__ pw1T)
{
    __shared__ float tile[32][33];
    const int tx = threadIdx.x & 31, ty = threadIdx.x >> 5;  // 32x8 threads
    const int k0 = blockIdx.x * 32, n0 = blockIdx.y * 32;
#pragma unroll
    for (int r = 0; r < 4; ++r) {
        const int row = ty + r * 8;
        tile[row][tx] = pw1[(size_t)(k0 + row) * P_HID + n0 + tx];
    }
    __syncthreads();
#pragma unroll
    for (int r = 0; r < 4; ++r) {
        const int row = ty + r * 8;  // n offset within tile
        pw1T[(size_t)(n0 + row) * K_TOT + k0 + tx] = f2bf(tile[tx][row]);
    }
}

// ---------------------------------------------------------------------------
// Kernel 3: hidden[b,n] = sum_{i,j} c[b,i] c[b,j] pw1[i*256+j, n]
// GEMM M=2048 N=512 K=65536, A generated on the fly (rank-1 per K-tile).
// Grid: 16 m-tiles x 4 n-tiles x 8 k-splits = 512 blocks, 256 threads.
// ---------------------------------------------------------------------------
__global__ __launch_bounds__(256, 2) void bilinear_gemm(
    const ushort* __restrict__ cbf, const ushort* __restrict__ pw1T,
    float* __restrict__ hidpart)
{
    __shared__ ushort Al[BM][BK + 8];   // +8 bf16 pad -> 144B row stride
    __shared__ ushort Bl[BN][BK + 8];

    const int bx = blockIdx.x;
    const int mt = bx & 15, nt = (bx >> 4) & 3, ks = bx >> 6;
    const int m0 = mt * BM, n0 = nt * BN;
    const int kb = ks * (K_TOT / KSPLIT), ke = kb + K_TOT / KSPLIT;

    const int tid = threadIdx.x, lane = tid & 63, wv = tid >> 6;
    const int wrow = (wv & 1) * 64, wcol = (wv >> 1) * 64;
    const int arow = tid >> 1, ajoff = (tid & 1) * 32;  // A-gen: 2 thr/row
    const int brow = tid >> 3, bcol = (tid & 7) * 8;    // B-load: 8 thr/row

    floatx4 acc[4][4];
#pragma unroll
    for (int i = 0; i < 4; ++i)
#pragma unroll
        for (int j = 0; j < 4; ++j) acc[i][j] = (floatx4){0.f, 0.f, 0.f, 0.f};

    const ushort* crow = cbf + (m0 + arow) * 256;

    for (int k0 = kb; k0 < ke; k0 += BK) {
        const int i0 = k0 >> 8;          // constant within a 64-wide K-tile
        const int j0 = k0 & 255;
        // ---- A-gen: Al[b][t] = c[b,i0] * c[b,j0+t], bf16 ----
        const float ci = bf2f(crow[i0]);
        const ushort* cj = crow + j0 + ajoff;
#pragma unroll
        for (int x = 0; x < 32; x += 8) {
            uint4 v = *(const uint4*)(cj + x);
            const ushort* sp = (const ushort*)&v;
            ushort o[8];
#pragma unroll
            for (int q = 0; q < 8; ++q) o[q] = f2bf(ci * bf2f(sp[q]));
            *(uint4*)&Al[arow][ajoff + x] = *(const uint4*)o;
        }
        // ---- B stage: Bl[n][k] from pw1T rows (contiguous 16B chunks) ----
        const ushort* bptr = pw1T + (size_t)(n0 + brow) * K_TOT + k0 + bcol;
#pragma unroll
        for (int p = 0; p < 4; ++p) {
            uint4 v = *(const uint4*)(bptr + (size_t)p * 32 * K_TOT);
            *(uint4*)&Bl[brow + p * 32][bcol] = v;
        }
        __syncthreads();
        // ---- MFMA: 2 k-steps of 32, 4x4 16x16 tiles per wave ----
#pragma unroll
        for (int kk = 0; kk < BK; kk += 32) {
            short8 af[4], bfr[4];
#pragma unroll
            for (int i = 0; i < 4; ++i)
                af[i] = *(const short8*)&Al[wrow + i * 16 + (lane & 15)][kk + (lane >> 4) * 8];
#pragma unroll
            for (int j = 0; j < 4; ++j)
                bfr[j] = *(const short8*)&Bl[wcol + j * 16 + (lane & 15)][kk + (lane >> 4) * 8];
#pragma unroll
            for (int i = 0; i < 4; ++i)
#pragma unroll
                for (int j = 0; j < 4; ++j)
                    acc[i][j] = __builtin_amdgcn_mfma_f32_16x16x32_bf16(
                        af[i], bfr[j], acc[i][j], 0, 0, 0);
        }
        __syncthreads();
    }

    // epilogue: C/D layout col=lane&15, row=(lane>>4)*4+r  (m89-verified)
    float* outp = hidpart + (size_t)ks * BATCH * P_HID;
    const int r0 = m0 + wrow + (lane >> 4) * 4;
    const int c0 = n0 + wcol + (lane & 15);
#pragma unroll
    for (int i = 0; i < 4; ++i)
#pragma unroll
        for (int j = 0; j < 4; ++j)
#pragma unroll
            for (int r = 0; r < 4; ++r)
                outp[(size_t)(r0 + i * 16 + r) * P_HID + c0 + j * 16] = acc[i][j][r];
}

// ---------------------------------------------------------------------------
// Kernel 4: sum k-splits + pb1, ReLU, dot with pw2, +pb2, sigmoid -> f32 out
// ---------------------------------------------------------------------------
__global__ void finalize(const float* __restrict__ hidpart,
                         const float* __restrict__ pb1,
                         const float* __restrict__ pw2,
                         const float* __restrict__ pb2,
                         float* __restrict__ out)
{
    const int b = blockIdx.x, t = threadIdx.x;  // 256 threads
    float accv = 0.f;
#pragma unroll
    for (int h = 0; h < 2; ++h) {
        const int n = t + h * 256;
        float v = 0.f;
#pragma unroll
        for (int s = 0; s < KSPLIT; ++s)
            v += hidpart[(size_t)s * BATCH * P_HID + (size_t)b * P_HID + n];
        v += pb1[n];
        v = fmaxf(v, 0.f);
        accv += v * pw2[n];
    }
#pragma unroll
    for (int off = 32; off; off >>= 1) accv += __shfl_down(accv, off, 64);
    __shared__ float red[4];
    const int lane = t & 63, wv = t >> 6;
    if (lane == 0) red[wv] = accv;
    __syncthreads();
    if (t == 0) {
        const float s = red[0] + red[1] + red[2] + red[3] + pb2[0];
        out[b] = 1.f / (1.f + expf(-s));   // fp32 output
    }
}

extern "C" void kernel_launch(void* const* d_in, const int* in_sizes, int n_in,
                              void* d_out, int out_size, void* d_ws, size_t ws_size,
                              hipStream_t stream)
{
    const float* dense  = (const float*)d_in[0];
    const int*   sparse = (const int*)d_in[1];
    // d_in[2] tokenizers == arange(CARD): gather index is the sparse value itself
    const float* emb = (const float*)d_in[3];
    const float* dw1 = (const float*)d_in[4];
    const float* db1 = (const float*)d_in[5];
    const float* dw2 = (const float*)d_in[6];
    const float* db2 = (const float*)d_in[7];
    const float* sw1 = (const float*)d_in[8];
    const float* sb1 = (const float*)d_in[9];
    const float* sw2 = (const float*)d_in[10];
    const float* sb2 = (const float*)d_in[11];
    const float* pw1 = (const float*)d_in[12];
    const float* pb1 = (const float*)d_in[13];
    const float* pw2 = (const float*)d_in[14];
    const float* pb2 = (const float*)d_in[15];

    char* ws = (char*)d_ws;
    ushort* cbf     = (ushort*)ws;                                   // 1 MB
    ushort* pw1T    = (ushort*)(ws + (1 << 20));                     // 64 MB
    float*  hidpart = (float*)(ws + (1 << 20) + ((size_t)64 << 20)); // 32 MB

    build_concat<<<BATCH, 64, 0, stream>>>(dense, sparse, emb, dw1, db1, dw2,
                                           db2, sw1, sb1, sw2, sb2, cbf);
    transpose_pw1<<<dim3(K_TOT / 32, P_HID / 32), 256, 0, stream>>>(pw1, pw1T);
    bilinear_gemm<<<16 * 4 * KSPLIT, 256, 0, stream>>>(cbf, pw1T, hidpart);
    finalize<<<BATCH, 256, 0, stream>>>(hidpart, pb1, pw2, pb2, (float*)d_out);
}

// Round 4
// 477.386 us; speedup vs baseline: 1.4590x; 1.4590x over previous
//
#include <hip/hip_runtime.h>
#include <hip/hip_bf16.h>
#include <hip/hip_fp16.h>
#include <math.h>

#define BATCH 2048
#define NFEAT 7
#define CARD 10000
#define CONCAT 256
#define P_HID 512
#define K_TOT 65536

#define BM 128
#define BN 128
#define BK 64
#define KSPLIT 16   // 16 mt x 4 nt x 16 ks = 1024 blocks -> 4 blocks/CU

using short8  = __attribute__((ext_vector_type(8))) short;
using floatx4 = __attribute__((ext_vector_type(4))) float;

__device__ __forceinline__ float bf2f(ushort u) {
    unsigned int x = ((unsigned int)u) << 16;
    return __builtin_bit_cast(float, x);
}
__device__ __forceinline__ ushort f2bf(float f) {
    unsigned int x = __builtin_bit_cast(unsigned int, f);
    x += 0x7fffu + ((x >> 16) & 1u);   // round-to-nearest-even
    return (ushort)(x >> 16);
}
// async global->LDS DMA, 16 B per lane; LDS dest = wave-uniform base + lane*16
__device__ __forceinline__ void dma16(const ushort* g, ushort* l) {
    __builtin_amdgcn_global_load_lds(
        (const __attribute__((address_space(1))) unsigned int*)g,
        (__attribute__((address_space(3))) unsigned int*)l,
        16, 0, 0);
}

// ---------------------------------------------------------------------------
// Kernel 1: dense MLP + embedding gather + per-feature sparse MLPs -> concat
// (bf16, row-major 2048x256). One wave per batch row.
// tokenizers == arange(CARD) -> gather index is the sparse value itself.
// ---------------------------------------------------------------------------
__global__ void build_concat(
    const float* __restrict__ dense, const int* __restrict__ sparse,
    const float* __restrict__ emb,
    const float* __restrict__ dw1, const float* __restrict__ db1,
    const float* __restrict__ dw2, const float* __restrict__ db2,
    const float* __restrict__ sw1, const float* __restrict__ sb1,
    const float* __restrict__ sw2, const float* __restrict__ sb2,
    ushort* __restrict__ cbf)
{
    __shared__ float xs[13];
    __shared__ float bufA[64];
    __shared__ float bufB[64];
    const int b = blockIdx.x, t = threadIdx.x;

    if (t < 13) xs[t] = dense[b * 13 + t];
    __syncthreads();

    float h = db1[t];
#pragma unroll
    for (int d = 0; d < 13; ++d) h += xs[d] * dw1[d * 64 + t];
    bufA[t] = fmaxf(h, 0.f);
    __syncthreads();

    if (t < 32) {
        float o = db2[t];
#pragma unroll
        for (int k = 0; k < 64; ++k) o += bufA[k] * dw2[k * 32 + t];
        cbf[b * 256 + t] = f2bf(o);
    }

    for (int f = 0; f < NFEAT; ++f) {
        __syncthreads();
        const int idx = sparse[b * NFEAT + f];
        bufB[t] = emb[((size_t)(f * CARD + idx)) * 64 + t];
        __syncthreads();
        float s = sb1[f * 64 + t];
#pragma unroll
        for (int e = 0; e < 64; ++e) s += bufB[e] * sw1[(f * 64 + e) * 64 + t];
        bufA[t] = fmaxf(s, 0.f);
        __syncthreads();
        if (t < 32) {
            float o = sb2[f * 32 + t];
#pragma unroll
            for (int k = 0; k < 64; ++k) o += bufA[k] * sw2[(f * 64 + k) * 32 + t];
            cbf[b * 256 + 32 + f * 32 + t] = f2bf(o);
        }
    }
}

// ---------------------------------------------------------------------------
// Kernel 2: pw1 (65536x512 f32) -> pw1T (512x65536 bf16), tiled transpose.
// ---------------------------------------------------------------------------
__global__ void transpose_pw1(const float* __restrict__ pw1,
                              ushort* __restrict__ pw1T)
{
    __shared__ float tile[32][33];
    const int tx = threadIdx.x & 31, ty = threadIdx.x >> 5;  // 32x8 threads
    const int k0 = blockIdx.x * 32, n0 = blockIdx.y * 32;
#pragma unroll
    for (int r = 0; r < 4; ++r) {
        const int row = ty + r * 8;
        tile[row][tx] = pw1[(size_t)(k0 + row) * P_HID + n0 + tx];
    }
    __syncthreads();
#pragma unroll
    for (int r = 0; r < 4; ++r) {
        const int row = ty + r * 8;  // n offset within tile
        pw1T[(size_t)(n0 + row) * K_TOT + k0 + tx] = f2bf(tile[tx][row]);
    }
}

// ---------------------------------------------------------------------------
// Kernel 3: hidden[b,n] = sum_{i,j} c[b,i] c[b,j] pw1[i*256+j, n]
// GEMM M=2048 N=512 K=65536, A generated on the fly (rank-1 per K-tile).
// 1024 blocks (4/CU), B staged via global_load_lds, XCD-swizzled for L2.
// ---------------------------------------------------------------------------
__global__ __launch_bounds__(256, 4) void bilinear_gemm(
    const ushort* __restrict__ cbf, const ushort* __restrict__ pw1T,
    __half* __restrict__ hidpart)
{
    __shared__ ushort Al[BM][BK + 8];   // 144 B stride (36 dw == 4 mod 32)
    __shared__ ushort Bl[BN][BK];       // packed 128 B rows (DMA-contiguous)

    // XCD-aware decode: 16 m-blocks of one (nt,ks) slice land on one XCD,
    // so the slice's 128n x 4096k bf16 (1 MB) stays L2-resident.
    const int b = blockIdx.x;
    const int xcd = b & 7, slot = b >> 3;
    const int mt = slot & 15;
    const int slice = ((slot >> 4) << 3) | xcd;   // 0..63
    const int nt = slice & 3, ks = slice >> 2;    // 4 n-tiles, 16 k-splits
    const int m0 = mt * BM, n0 = nt * BN;
    const int kb = ks * (K_TOT / KSPLIT), ke = kb + K_TOT / KSPLIT;

    const int tid = threadIdx.x, lane = tid & 63, wv = tid >> 6;
    const int wrow = (wv & 1) * 64, wcol = (wv >> 1) * 64;
    const int arow = tid >> 1, ajoff = (tid & 1) * 32;  // A-gen: 2 thr/row

    floatx4 acc[4][4];
#pragma unroll
    for (int i = 0; i < 4; ++i)
#pragma unroll
        for (int j = 0; j < 4; ++j) acc[i][j] = (floatx4){0.f, 0.f, 0.f, 0.f};

    const ushort* crow = cbf + (m0 + arow) * 256;
    // per-lane DMA source: row = n0 + wv*32 + (lane>>3) (+8 per issue p)
    const int drow = wv * 32 + (lane >> 3);
    const ushort* bsrc = pw1T + (size_t)(n0 + drow) * K_TOT + kb + (lane & 7) * 8;
    ushort* bdst = &Bl[wv * 32][0];   // wave-uniform; HW adds lane*16

    for (int k0 = kb; k0 < ke; k0 += BK) {
        // ---- B stage: async DMA, 4 x 1KB issues per wave (16 KB total) ----
#pragma unroll
        for (int p = 0; p < 4; ++p)
            dma16(bsrc + (size_t)(p * 8) * K_TOT, bdst + (p * 8) * BK);
        bsrc += BK;

        // ---- A-gen (overlaps DMA): Al[b][t] = c[b,i0] * c[b,j0+t] ----
        const int i0 = k0 >> 8;
        const int j0 = k0 & 255;
        const float ci = bf2f(crow[i0]);
        const ushort* cj = crow + j0 + ajoff;
#pragma unroll
        for (int x = 0; x < 32; x += 8) {
            uint4 v = *(const uint4*)(cj + x);
            const ushort* sp = (const ushort*)&v;
            ushort o[8];
#pragma unroll
            for (int q = 0; q < 8; ++q) o[q] = f2bf(ci * bf2f(sp[q]));
            *(uint4*)&Al[arow][ajoff + x] = *(const uint4*)o;
        }
        __syncthreads();   // drains vmcnt (DMA) + lgkm (A writes)

        // ---- MFMA: 2 k-steps of 32, 4x4 16x16 tiles per wave ----
#pragma unroll
        for (int kk = 0; kk < BK; kk += 32) {
            short8 af[4], bfr[4];
#pragma unroll
            for (int i = 0; i < 4; ++i)
                af[i] = *(const short8*)&Al[wrow + i * 16 + (lane & 15)][kk + (lane >> 4) * 8];
#pragma unroll
            for (int j = 0; j < 4; ++j)
                bfr[j] = *(const short8*)&Bl[wcol + j * 16 + (lane & 15)][kk + (lane >> 4) * 8];
#pragma unroll
            for (int i = 0; i < 4; ++i)
#pragma unroll
                for (int j = 0; j < 4; ++j)
                    acc[i][j] = __builtin_amdgcn_mfma_f32_16x16x32_bf16(
                        af[i], bfr[j], acc[i][j], 0, 0, 0);
        }
        __syncthreads();
    }

    // epilogue: C/D layout col=lane&15, row=(lane>>4)*4+r (m89-verified)
    __half* outp = hidpart + (size_t)ks * BATCH * P_HID;
    const int r0 = m0 + wrow + (lane >> 4) * 4;
    const int c0 = n0 + wcol + (lane & 15);
#pragma unroll
    for (int i = 0; i < 4; ++i)
#pragma unroll
        for (int j = 0; j < 4; ++j)
#pragma unroll
            for (int r = 0; r < 4; ++r)
                outp[(size_t)(r0 + i * 16 + r) * P_HID + c0 + j * 16] =
                    __float2half(acc[i][j][r]);
}

// ---------------------------------------------------------------------------
// Kernel 4: sum k-splits + pb1, ReLU, dot with pw2, +pb2, sigmoid -> f32 out
// ---------------------------------------------------------------------------
__global__ void finalize(const __half* __restrict__ hidpart,
                         const float* __restrict__ pb1,
                         const float* __restrict__ pw2,
                         const float* __restrict__ pb2,
                         float* __restrict__ out)
{
    const int b = blockIdx.x, t = threadIdx.x;  // 256 threads
    float accv = 0.f;
#pragma unroll
    for (int h = 0; h < 2; ++h) {
        const int n = t + h * 256;
        float v = 0.f;
#pragma unroll
        for (int s = 0; s < KSPLIT; ++s)
            v += __half2float(hidpart[(size_t)s * BATCH * P_HID + (size_t)b * P_HID + n]);
        v += pb1[n];
        v = fmaxf(v, 0.f);
        accv += v * pw2[n];
    }
#pragma unroll
    for (int off = 32; off; off >>= 1) accv += __shfl_down(accv, off, 64);
    __shared__ float red[4];
    const int lane = t & 63, wv = t >> 6;
    if (lane == 0) red[wv] = accv;
    __syncthreads();
    if (t == 0) {
        const float s = red[0] + red[1] + red[2] + red[3] + pb2[0];
        out[b] = 1.f / (1.f + expf(-s));
    }
}

extern "C" void kernel_launch(void* const* d_in, const int* in_sizes, int n_in,
                              void* d_out, int out_size, void* d_ws, size_t ws_size,
                              hipStream_t stream)
{
    const float* dense  = (const float*)d_in[0];
    const int*   sparse = (const int*)d_in[1];
    // d_in[2] tokenizers == arange(CARD): gather index is the sparse value itself
    const float* emb = (const float*)d_in[3];
    const float* dw1 = (const float*)d_in[4];
    const float* db1 = (const float*)d_in[5];
    const float* dw2 = (const float*)d_in[6];
    const float* db2 = (const float*)d_in[7];
    const float* sw1 = (const float*)d_in[8];
    const float* sb1 = (const float*)d_in[9];
    const float* sw2 = (const float*)d_in[10];
    const float* sb2 = (const float*)d_in[11];
    const float* pw1 = (const float*)d_in[12];
    const float* pb1 = (const float*)d_in[13];
    const float* pw2 = (const float*)d_in[14];
    const float* pb2 = (const float*)d_in[15];

    char* ws = (char*)d_ws;
    ushort* cbf      = (ushort*)ws;                                   // 1 MB
    ushort* pw1T     = (ushort*)(ws + (1 << 20));                     // 64 MB
    __half* hidpart  = (__half*)(ws + (1 << 20) + ((size_t)64 << 20)); // 32 MB (fp16, 16 splits)

    build_concat<<<BATCH, 64, 0, stream>>>(dense, sparse, emb, dw1, db1, dw2,
                                           db2, sw1, sb1, sw2, sb2, cbf);
    transpose_pw1<<<dim3(K_TOT / 32, P_HID / 32), 256, 0, stream>>>(pw1, pw1T);
    bilinear_gemm<<<16 * 4 * KSPLIT, 256, 0, stream>>>(cbf, pw1T, hidpart);
    finalize<<<BATCH, 256, 0, stream>>>(hidpart, pb1, pw2, pb2, (float*)d_out);
}

// Round 5
// 436.288 us; speedup vs baseline: 1.5964x; 1.0942x over previous
//
#include <hip/hip_runtime.h>
#include <hip/hip_fp16.h>
#include <math.h>

#define BATCH 2048
#define NFEAT 7
#define CARD 10000
#define CONCAT 256
#define P_HID 512
#define K_TOT 65536

#define BM 128
#define BN 128
#define BK 64
#define KSPLIT 16   // 16 mt x 4 nt x 16 ks = 1024 blocks -> 4 blocks/CU

#define TBLKS 8192  // transpose blocks: (65536/64) * (512/64)

using half8   = __attribute__((ext_vector_type(8))) _Float16;
using floatx4 = __attribute__((ext_vector_type(4))) float;

// async global->LDS DMA, 16 B per lane; LDS dest = wave-uniform base + lane*16
__device__ __forceinline__ void dma16(const _Float16* g, _Float16* l) {
    __builtin_amdgcn_global_load_lds(
        (const __attribute__((address_space(1))) unsigned int*)g,
        (__attribute__((address_space(3))) unsigned int*)l,
        16, 0, 0);
}

// ---------------------------------------------------------------------------
// Kernel 1 (fused): blockIdx < TBLKS  -> pw1 (65536x512 f32) -> fp16 transpose
//                   blockIdx >= TBLKS -> dense MLP + gather + sparse MLPs
// tokenizers == arange(CARD) -> gather index is the sparse value itself.
// ---------------------------------------------------------------------------
__global__ __launch_bounds__(256) void fused_pre(
    const float* __restrict__ dense, const int* __restrict__ sparse,
    const float* __restrict__ emb,
    const float* __restrict__ dw1, const float* __restrict__ db1,
    const float* __restrict__ dw2, const float* __restrict__ db2,
    const float* __restrict__ sw1, const float* __restrict__ sb1,
    const float* __restrict__ sw2, const float* __restrict__ sb2,
    const float* __restrict__ pw1,
    _Float16* __restrict__ cbf, _Float16* __restrict__ pw1T)
{
    __shared__ float smem[64 * 67];   // 17.2 KB; stride 67 dw -> <=2-way banks
    const int tid = threadIdx.x;

    if (blockIdx.x < TBLKS) {
        // ---- 64(k) x 64(n) transpose tile, fp32 -> fp16 ----
        const int bk = blockIdx.x & 1023, bn = blockIdx.x >> 10;
        const int k0 = bk * 64, n0 = bn * 64;
        const int c = tid & 15, r = tid >> 4;       // float4 col, row
#pragma unroll
        for (int p = 0; p < 4; ++p) {
            const int row = r + p * 16;
            const float4 v = *(const float4*)&pw1[(size_t)(k0 + row) * P_HID + n0 + c * 4];
            float* dst = &smem[row * 67 + c * 4];
            dst[0] = v.x; dst[1] = v.y; dst[2] = v.z; dst[3] = v.w;
        }
        __syncthreads();
        const int e = tid & 7, nn = tid >> 3;       // 16B k-chunk, n-row
#pragma unroll
        for (int p = 0; p < 2; ++p) {
            const int n = nn + p * 32;
            half8 o;
#pragma unroll
            for (int q = 0; q < 8; ++q)
                o[q] = (_Float16)smem[(8 * e + q) * 67 + n];
            *(half8*)(pw1T + (size_t)(n0 + n) * K_TOT + k0 + 8 * e) = o;
        }
    } else {
        // ---- concat build: 4 batch rows per block, one wave per row ----
        const int wv = tid >> 6, t = tid & 63;
        const int b = (blockIdx.x - TBLKS) * 4 + wv;
        float* xs   = smem + wv * 13;
        float* bufA = smem + 64  + wv * 64;
        float* bufB = smem + 320 + wv * 64;

        if (t < 13) xs[t] = dense[b * 13 + t];
        __syncthreads();

        float h = db1[t];
#pragma unroll
        for (int d = 0; d < 13; ++d) h += xs[d] * dw1[d * 64 + t];
        bufA[t] = fmaxf(h, 0.f);
        __syncthreads();

        if (t < 32) {
            float o = db2[t];
#pragma unroll
            for (int k = 0; k < 64; ++k) o += bufA[k] * dw2[k * 32 + t];
            cbf[b * 256 + t] = (_Float16)o;
        }

        for (int f = 0; f < NFEAT; ++f) {
            __syncthreads();
            const int idx = sparse[b * NFEAT + f];
            bufB[t] = emb[((size_t)(f * CARD + idx)) * 64 + t];
            __syncthreads();
            float s = sb1[f * 64 + t];
#pragma unroll
            for (int e2 = 0; e2 < 64; ++e2) s += bufB[e2] * sw1[(f * 64 + e2) * 64 + t];
            bufA[t] = fmaxf(s, 0.f);
            __syncthreads();
            if (t < 32) {
                float o = sb2[f * 32 + t];
#pragma unroll
                for (int k = 0; k < 64; ++k) o += bufA[k] * sw2[(f * 64 + k) * 32 + t];
                cbf[b * 256 + 32 + f * 32 + t] = (_Float16)o;
            }
        }
    }
}

// ---------------------------------------------------------------------------
// Kernel 2: hidden[b,n] = sum_{i,j} c[b,i] c[b,j] pw1[i*256+j, n]
// fp16 GEMM M=2048 N=512 K=65536; A generated on the fly (rank-1 per K-tile,
// v_pk_mul_f16); B via global_load_lds with XOR-swizzled LDS slots
// (slot = chunk ^ (row&7)) so fragment reads hit all 32 banks uniformly.
// ---------------------------------------------------------------------------
__global__ __launch_bounds__(256, 4) void bilinear_gemm(
    const _Float16* __restrict__ cbf, const _Float16* __restrict__ pw1T,
    _Float16* __restrict__ hidpart)
{
    __shared__ _Float16 Al[BM][BK + 8];   // 144 B stride -> uniform banks
    __shared__ _Float16 Bl[BN][BK];       // packed 128 B rows, XOR-swizzled

    // XCD-aware decode: 16 m-blocks of one (nt,ks) slice land on one XCD,
    // so the slice's 1 MB of pw1T stays L2-resident.
    const int b = blockIdx.x;
    const int xcd = b & 7, slot = b >> 3;
    const int mt = slot & 15;
    const int slice = ((slot >> 4) << 3) | xcd;   // 0..63
    const int nt = slice & 3, ks = slice >> 2;
    const int m0 = mt * BM, n0 = nt * BN;
    const int kb = ks * (K_TOT / KSPLIT), ke = kb + K_TOT / KSPLIT;

    const int tid = threadIdx.x, lane = tid & 63, wv = tid >> 6;
    const int wrow = (wv & 1) * 64, wcol = (wv >> 1) * 64;
    const int arow = tid >> 1, ajoff = (tid & 1) * 32;  // A-gen: 2 thr/row

    floatx4 acc[4][4];
#pragma unroll
    for (int i = 0; i < 4; ++i)
#pragma unroll
        for (int j = 0; j < 4; ++j) acc[i][j] = (floatx4){0.f, 0.f, 0.f, 0.f};

    const _Float16* crow = cbf + (m0 + arow) * 256;
    // DMA: lane l -> row (l>>3) of its 8-row group, LDS slot (l&7).
    // Slot s holds global k-chunk (s ^ (row&7)) -> fetch that chunk.
    const int drow = wv * 32 + (lane >> 3);
    const int eswz = (lane & 7) ^ ((lane >> 3) & 7);
    const _Float16* bsrc = pw1T + (size_t)(n0 + drow) * K_TOT + kb + eswz * 8;
    _Float16* bdst = &Bl[wv * 32][0];   // wave-uniform; HW adds lane*16B

    for (int k0 = kb; k0 < ke; k0 += BK) {
        // ---- B stage: async DMA, 4 x 1KB issues per wave ----
#pragma unroll
        for (int p = 0; p < 4; ++p)
            dma16(bsrc + (size_t)(p * 8) * K_TOT, bdst + (p * 8) * BK);
        bsrc += BK;

        // ---- A-gen (overlaps DMA): Al[r][t] = c[r,i0] * c[r,j0+t], fp16 ----
        const int i0 = k0 >> 8;
        const int j0 = k0 & 255;
        const _Float16 ci = crow[i0];
        const half8 civ = {ci, ci, ci, ci, ci, ci, ci, ci};
        const _Float16* cj = crow + j0 + ajoff;
#pragma unroll
        for (int x = 0; x < 32; x += 8) {
            half8 v = *(const half8*)(cj + x);
            *(half8*)&Al[arow][ajoff + x] = v * civ;   // 4x v_pk_mul_f16
        }
        __syncthreads();   // drains vmcnt (DMA) + lgkm (A writes)

        // ---- MFMA: 2 k-steps of 32, 4x4 16x16 tiles per wave ----
#pragma unroll
        for (int kk = 0; kk < BK; kk += 32) {
            half8 af[4], bfr[4];
#pragma unroll
            for (int i = 0; i < 4; ++i)
                af[i] = *(const half8*)&Al[wrow + i * 16 + (lane & 15)][kk + (lane >> 4) * 8];
#pragma unroll
            for (int j = 0; j < 4; ++j) {
                const int s = (((kk >> 3) + (lane >> 4)) ^ (lane & 7)) * 8;
                bfr[j] = *(const half8*)&Bl[wcol + j * 16 + (lane & 15)][s];
            }
#pragma unroll
            for (int i = 0; i < 4; ++i)
#pragma unroll
                for (int j = 0; j < 4; ++j)
                    acc[i][j] = __builtin_amdgcn_mfma_f32_16x16x32_f16(
                        af[i], bfr[j], acc[i][j], 0, 0, 0);
        }
        __syncthreads();
    }

    // epilogue: C/D layout col=lane&15, row=(lane>>4)*4+r (m89-verified)
    _Float16* outp = hidpart + (size_t)ks * BATCH * P_HID;
    const int r0 = m0 + wrow + (lane >> 4) * 4;
    const int c0 = n0 + wcol + (lane & 15);
#pragma unroll
    for (int i = 0; i < 4; ++i)
#pragma unroll
        for (int j = 0; j < 4; ++j)
#pragma unroll
            for (int r = 0; r < 4; ++r)
                outp[(size_t)(r0 + i * 16 + r) * P_HID + c0 + j * 16] =
                    (_Float16)acc[i][j][r];
}

// ---------------------------------------------------------------------------
// Kernel 3: sum k-splits + pb1, ReLU, dot with pw2, +pb2, sigmoid -> f32 out
// ---------------------------------------------------------------------------
__global__ void finalize(const _Float16* __restrict__ hidpart,
                         const float* __restrict__ pb1,
                         const float* __restrict__ pw2,
                         const float* __restrict__ pb2,
                         float* __restrict__ out)
{
    const int b = blockIdx.x, t = threadIdx.x;  // 256 threads
    float accv = 0.f;
#pragma unroll
    for (int h = 0; h < 2; ++h) {
        const int n = t + h * 256;
        float v = 0.f;
#pragma unroll
        for (int s = 0; s < KSPLIT; ++s)
            v += (float)hidpart[(size_t)s * BATCH * P_HID + (size_t)b * P_HID + n];
        v += pb1[n];
        v = fmaxf(v, 0.f);
        accv += v * pw2[n];
    }
#pragma unroll
    for (int off = 32; off; off >>= 1) accv += __shfl_down(accv, off, 64);
    __shared__ float red[4];
    const int lane = t & 63, wv = t >> 6;
    if (lane == 0) red[wv] = accv;
    __syncthreads();
    if (t == 0) {
        const float s = red[0] + red[1] + red[2] + red[3] + pb2[0];
        out[b] = 1.f / (1.f + expf(-s));
    }
}

extern "C" void kernel_launch(void* const* d_in, const int* in_sizes, int n_in,
                              void* d_out, int out_size, void* d_ws, size_t ws_size,
                              hipStream_t stream)
{
    const float* dense  = (const float*)d_in[0];
    const int*   sparse = (const int*)d_in[1];
    // d_in[2] tokenizers == arange(CARD): gather index is the sparse value itself
    const float* emb = (const float*)d_in[3];
    const float* dw1 = (const float*)d_in[4];
    const float* db1 = (const float*)d_in[5];
    const float* dw2 = (const float*)d_in[6];
    const float* db2 = (const float*)d_in[7];
    const float* sw1 = (const float*)d_in[8];
    const float* sb1 = (const float*)d_in[9];
    const float* sw2 = (const float*)d_in[10];
    const float* sb2 = (const float*)d_in[11];
    const float* pw1 = (const float*)d_in[12];
    const float* pb1 = (const float*)d_in[13];
    const float* pw2 = (const float*)d_in[14];
    const float* pb2 = (const float*)d_in[15];

    char* ws = (char*)d_ws;
    _Float16* cbf     = (_Float16*)ws;                                   // 1 MB
    _Float16* pw1T    = (_Float16*)(ws + (1 << 20));                     // 64 MB
    _Float16* hidpart = (_Float16*)(ws + (1 << 20) + ((size_t)64 << 20)); // 32 MB

    fused_pre<<<TBLKS + BATCH / 4, 256, 0, stream>>>(
        dense, sparse, emb, dw1, db1, dw2, db2, sw1, sb1, sw2, sb2, pw1,
        cbf, pw1T);
    bilinear_gemm<<<16 * 4 * KSPLIT, 256, 0, stream>>>(cbf, pw1T, hidpart);
    finalize<<<BATCH, 256, 0, stream>>>(hidpart, pb1, pw2, pb2, (float*)d_out);
}